// Round 6
// baseline (174.813 us; speedup 1.0000x reference)
//
#include <hip/hip_runtime.h>
#include <math.h>
#include <stdint.h>

#define H 2048
#define HH (H * H)
#define NB 256
#define NBK 1024                // buckets per side
#define RPIX (HH / NBK)         // 4096 pixels per region
#define RQUAD (RPIX / 4)        // 1024 quads per region
#define RLOG 12                 // log2(RPIX)
#define BCAP 2304               // mean 1953, sigma ~44 -> +8 sigma; spill path guards
#define SPT 8                   // samples per thread in bucket pass

// ws layout (fast path):
//   [0]       double accum               (8 B)
//   [64]      uint32 hist8[8][6*256]     (48 KiB)  8 slices to cut atomic chains
//   [49216]   uint32 gcnt[2048]          (8 KiB)   dst 0..1023, ref 1024..2047
//   [57408]   float  table[3][256]       (3 KiB)
//   [65536]   uint32 bits[HH/32]         (512 KiB) membership bitmask
//   [1 MiB]   u16    dlist[1024][BCAP]   (4.5 MiB)
//   [6 MiB]   u16    rlist[1024][BCAP]   (4.5 MiB)
#define OFF_HIST8 64
#define OFF_GCNT  49216
#define OFF_TABLE 57408
#define OFF_BITS  65536
#define OFF_DLIST ((size_t)1 << 20)
#define OFF_RLIST ((size_t)6 << 20)
#define WS_FAST   ((size_t)11 << 20)

__global__ void k_init(uint32_t* __restrict__ ws32) {
    int tid = blockIdx.x * blockDim.x + threadIdx.x;
    int stride = gridDim.x * blockDim.x;
    uint4 z = {0u, 0u, 0u, 0u};
    // zero [0, 60480): accum + hist8 + gcnt + table  (3780 uint4)
    uint4* a = (uint4*)ws32;
    for (int i = tid; i < 3780; i += stride) a[i] = z;
    // zero bits: 32768 uint4
    uint4* b = (uint4*)((char*)ws32 + OFF_BITS);
    for (int i = tid; i < 32768; i += stride) b[i] = z;
}

__device__ __forceinline__ float de_norm255(float x) {
    return fminf(fmaxf((x + 1.0f) * 0.5f, 0.0f), 1.0f) * 255.0f;
}

__device__ __forceinline__ uint32_t bin_of(float v, float m) {
    return (uint32_t)(de_norm255(v) * m);  // in [0,255], trunc==floor
}

#define E4(v, e) ((e) == 0 ? (v).x : (e) == 1 ? (v).y : (e) == 2 ? (v).z : (v).w)

// Partition sample positions into 1024 regions per side; store u16 local offsets.
__global__ void k_bucket(const int* __restrict__ i0, const int* __restrict__ i1,
                         const int* __restrict__ i2, const int* __restrict__ i3,
                         unsigned short* __restrict__ dlist,
                         unsigned short* __restrict__ rlist,
                         uint32_t* __restrict__ gcnt,
                         const float* __restrict__ ref, const float* __restrict__ msrc,
                         const float* __restrict__ tgt, const float* __restrict__ mtar,
                         uint32_t* __restrict__ hist8, uint32_t* __restrict__ bits,
                         int noct) {
    __shared__ uint32_t lcnt[2 * NBK];
    __shared__ uint32_t lbase[2 * NBK];
    for (int i = threadIdx.x; i < 2 * NBK; i += blockDim.x) lcnt[i] = 0u;
    __syncthreads();
    int q = blockIdx.x * blockDim.x + threadIdx.x;
    bool act = q < noct;
    int pa[SPT], pb[SPT];
    uint32_t sa[SPT], sb[SPT];
    if (act) {
        int4 a0 = ((const int4*)i0)[2 * q], a1 = ((const int4*)i0)[2 * q + 1];
        int4 b0 = ((const int4*)i1)[2 * q], b1 = ((const int4*)i1)[2 * q + 1];
        int4 c0 = ((const int4*)i2)[2 * q], c1 = ((const int4*)i2)[2 * q + 1];
        int4 d0 = ((const int4*)i3)[2 * q], d1 = ((const int4*)i3)[2 * q + 1];
        pa[0] = a0.x * H + b0.x; pa[1] = a0.y * H + b0.y;
        pa[2] = a0.z * H + b0.z; pa[3] = a0.w * H + b0.w;
        pa[4] = a1.x * H + b1.x; pa[5] = a1.y * H + b1.y;
        pa[6] = a1.z * H + b1.z; pa[7] = a1.w * H + b1.w;
        pb[0] = c0.x * H + d0.x; pb[1] = c0.y * H + d0.y;
        pb[2] = c0.z * H + d0.z; pb[3] = c0.w * H + d0.w;
        pb[4] = c1.x * H + d1.x; pb[5] = c1.y * H + d1.y;
        pb[6] = c1.z * H + d1.z; pb[7] = c1.w * H + d1.w;
#pragma unroll
        for (int j = 0; j < SPT; ++j) {
            sa[j] = atomicAdd(&lcnt[pa[j] >> RLOG], 1u);
            sb[j] = atomicAdd(&lcnt[NBK + (pb[j] >> RLOG)], 1u);
        }
    }
    __syncthreads();
    for (int i = threadIdx.x; i < 2 * NBK; i += blockDim.x)
        lbase[i] = lcnt[i] ? atomicAdd(&gcnt[i], lcnt[i]) : 0u;
    __syncthreads();
    if (!act) return;
    uint32_t* hs = hist8 + (blockIdx.x & 7) * 1536;
#pragma unroll
    for (int j = 0; j < SPT; ++j) {
        int p = pa[j];
        int bk = p >> RLOG;
        uint32_t s = lbase[bk] + sa[j];
        if (s < BCAP) {
            dlist[(size_t)bk * BCAP + s] = (unsigned short)(p & (RPIX - 1));
        } else {  // spill: statistically never
            float m = msrc[p];
            atomicOr(&bits[p >> 5], 1u << (p & 31));
#pragma unroll
            for (int c = 0; c < 3; ++c)
                atomicAdd(&hs[c * NB + bin_of(ref[c * HH + p], m)], 1u);
        }
        p = pb[j];
        bk = p >> RLOG;
        s = lbase[NBK + bk] + sb[j];
        if (s < BCAP) {
            rlist[(size_t)bk * BCAP + s] = (unsigned short)(p & (RPIX - 1));
        } else {
            float m = mtar[p];
#pragma unroll
            for (int c = 0; c < 3; ++c)
                atomicAdd(&hs[768 + c * NB + bin_of(tgt[c * HH + p], m)], 1u);
        }
    }
}

// One block per (side, bucket). Phase A: scatter list into LDS counts.
// Phase B: stream region floats coalesced, add count-weighted histogram entries.
__global__ __launch_bounds__(256, 8) void k_bgather(
    const unsigned short* __restrict__ dlist, const unsigned short* __restrict__ rlist,
    const uint32_t* __restrict__ gcnt,
    const float* __restrict__ ref, const float* __restrict__ msrc,
    const float* __restrict__ tgt, const float* __restrict__ mtar,
    uint32_t* __restrict__ hist8, uint32_t* __restrict__ bits) {
    __shared__ uint32_t s_cnt[RPIX];         // 16 KiB per-pixel hit counts
    __shared__ uint32_t s_bits[RPIX / 32];   // 512 B membership
    __shared__ uint32_t s_h[3 * NB];         // 3 KiB histogram
    int bid = blockIdx.x;
    int isref = bid >= NBK;
    int b = isref ? bid - NBK : bid;
    const float* v = isref ? tgt : ref;
    const float* m = isref ? mtar : msrc;
    for (int i = threadIdx.x; i < RPIX; i += blockDim.x) s_cnt[i] = 0u;
    for (int i = threadIdx.x; i < 3 * NB; i += blockDim.x) s_h[i] = 0u;
    if (!isref)
        for (int i = threadIdx.x; i < RPIX / 32; i += blockDim.x) s_bits[i] = 0u;
    __syncthreads();
    // Phase A: list -> LDS counts (no staging dependency)
    uint32_t n = min(gcnt[bid], (uint32_t)BCAP);
    const unsigned short* list = (isref ? rlist : dlist) + (size_t)b * BCAP;
    for (uint32_t i = threadIdx.x; i < n; i += blockDim.x)
        atomicAdd(&s_cnt[list[i]], 1u);
    __syncthreads();
    // Phase B: stream region, weighted hist adds
    uint32_t z0 = 0, z1 = 0, z2 = 0;
    int qbase = b * RQUAD;
    for (int qi = threadIdx.x; qi < RQUAD; qi += blockDim.x) {
        uint4 cw = ((const uint4*)s_cnt)[qi];
        if ((cw.x | cw.y | cw.z | cw.w) == 0u) continue;
        float4 m4 = ((const float4*)m)[qbase + qi];
        float4 v0 = ((const float4*)(v))[qbase + qi];
        float4 v1 = ((const float4*)(v + HH))[qbase + qi];
        float4 v2 = ((const float4*)(v + 2 * HH))[qbase + qi];
        uint32_t cnts[4] = {cw.x, cw.y, cw.z, cw.w};
#pragma unroll
        for (int e = 0; e < 4; ++e) {
            uint32_t cn = cnts[e];
            if (!cn) continue;
            float mm = E4(m4, e);
            uint32_t b0 = bin_of(E4(v0, e), mm);
            uint32_t b1 = bin_of(E4(v1, e), mm);
            uint32_t b2 = bin_of(E4(v2, e), mm);
            if (b0) atomicAdd(&s_h[b0], cn); else z0 += cn;
            if (b1) atomicAdd(&s_h[NB + b1], cn); else z1 += cn;
            if (b2) atomicAdd(&s_h[2 * NB + b2], cn); else z2 += cn;
        }
        if (!isref) {
            uint32_t nib = (cnts[0] ? 1u : 0u) | (cnts[1] ? 2u : 0u) |
                           (cnts[2] ? 4u : 0u) | (cnts[3] ? 8u : 0u);
            atomicOr(&s_bits[qi >> 3], nib << ((qi & 7) * 4));
        }
    }
    if (z0) atomicAdd(&s_h[0], z0);
    if (z1) atomicAdd(&s_h[NB], z1);
    if (z2) atomicAdd(&s_h[2 * NB], z2);
    __syncthreads();
    uint32_t* hs = hist8 + (blockIdx.x & 7) * 1536 + (isref ? 768 : 0);
    for (int i = threadIdx.x; i < 3 * NB; i += blockDim.x)
        if (s_h[i]) atomicAdd(&hs[i], s_h[i]);
    if (!isref) {
        uint32_t* gb = bits + b * (RPIX / 32);
        for (int i = threadIdx.x; i < RPIX / 32; i += blockDim.x)
            if (s_bits[i]) atomicOr(&gb[i], s_bits[i]);
    }
}

// Monolithic fallback (any ws): gather floats via LLC + bits mask.
__global__ void k_hist_fb(const float* __restrict__ tgt, const float* __restrict__ ref,
                          const float* __restrict__ msrc, const float* __restrict__ mtar,
                          const int* __restrict__ i0, const int* __restrict__ i1,
                          const int* __restrict__ i2, const int* __restrict__ i3,
                          uint32_t* __restrict__ hist8, uint32_t* __restrict__ bits,
                          int nidx) {
    __shared__ uint32_t lh[6 * NB];
    for (int i = threadIdx.x; i < 6 * NB; i += blockDim.x) lh[i] = 0u;
    __syncthreads();
    int stride = gridDim.x * blockDim.x;
    for (int k = blockIdx.x * blockDim.x + threadIdx.x; k < nidx; k += stride) {
        int pa = i0[k] * H + i1[k];
        int pb = i2[k] * H + i3[k];
        float ms = msrc[pa];
        float mt = mtar[pb];
        atomicOr(&bits[pa >> 5], 1u << (pa & 31));
#pragma unroll
        for (int c = 0; c < 3; ++c) {
            atomicAdd(&lh[c * NB + bin_of(ref[c * HH + pa], ms)], 1u);
            atomicAdd(&lh[(3 + c) * NB + bin_of(tgt[c * HH + pb], mt)], 1u);
        }
    }
    __syncthreads();
    uint32_t* hs = hist8 + (blockIdx.x & 7) * 1536;
    for (int i = threadIdx.x; i < 6 * NB; i += blockDim.x)
        if (lh[i]) atomicAdd(&hs[i], lh[i]);
}

// 3 blocks (one per channel) x 256 threads; sums the 8 hist slices.
__global__ void k_table(const uint32_t* __restrict__ hist8, float* __restrict__ table) {
    int c = blockIdx.x;
    int t = threadIdx.x;
    __shared__ uint32_t cdd[NB], crr[NB];
    __shared__ float r[NB], a[NB];
    uint32_t sd = 0, sr = 0;
#pragma unroll
    for (int x = 0; x < 8; ++x) {
        sd += hist8[x * 1536 + c * NB + t];
        sr += hist8[x * 1536 + 768 + c * NB + t];
    }
    cdd[t] = sd;
    crr[t] = sr;
    __syncthreads();
    if (t == 0) {
        uint32_t s = 0;
        for (int i = 0; i < NB; ++i) { s += cdd[i]; cdd[i] = s; }
        s = 0;
        for (int i = 0; i < NB; ++i) { s += crr[i]; crr[i] = s; }
    }
    __syncthreads();
    float totd = (float)cdd[NB - 1];
    float totr = (float)crr[NB - 1];
    r[t] = (float)cdd[t] / totd;
    a[t] = (float)crr[t] / totr;
    __syncthreads();
    float out;
    if (t == 0) {
        out = 0.0f;
    } else if (t == NB - 1) {
        out = (float)(NB - 1);
    } else {
        float ri = r[t];
        int j = -1;
        for (int jj = 0; jj < NB - 1; ++jj) {
            if (ri >= a[jj] && ri <= a[jj + 1]) { j = jj; break; }
        }
        out = (j >= 0) ? (float)(j + 1) : (float)t;
    }
    table[c * NB + t] = out;
}

// float4-vectorized loss; membership from bits; table in LDS.
__global__ void k_loss(const float* __restrict__ inp, const float* __restrict__ ref,
                       const float* __restrict__ msrc, const uint32_t* __restrict__ bits,
                       const float* __restrict__ table, double* __restrict__ accum) {
    __shared__ float tl[3 * NB];
    for (int i = threadIdx.x; i < 3 * NB; i += blockDim.x) tl[i] = table[i];
    __syncthreads();
    float part = 0.0f;
    int stride = gridDim.x * blockDim.x;
    for (int q = blockIdx.x * blockDim.x + threadIdx.x; q < HH / 4; q += stride) {
        float4 m4 = ((const float4*)msrc)[q];
        uint32_t nib = bits[q >> 3] >> ((q & 7) * 4);
#pragma unroll
        for (int c = 0; c < 3; ++c) {
            float4 iv = ((const float4*)(inp + c * HH))[q];
            float4 rv = ((const float4*)(ref + c * HH))[q];
#pragma unroll
            for (int e = 0; e < 4; ++e) {
                float m = E4(m4, e);
                float im = de_norm255(E4(iv, e)) * m;
                float r = de_norm255(E4(rv, e)) * m;
                float match;
                if ((nib >> e) & 1u)
                    match = tl[c * NB + (int)fminf(fmaxf(r, 0.0f), 255.0f)];
                else
                    match = r;
                part += fabsf(im - match);
            }
        }
    }
#pragma unroll
    for (int off = 32; off > 0; off >>= 1) part += __shfl_down(part, off);
    __shared__ float wsum[4];
    int lane = threadIdx.x & 63;
    int wid = threadIdx.x >> 6;
    if (lane == 0) wsum[wid] = part;
    __syncthreads();
    if (threadIdx.x == 0)
        atomicAdd(accum, (double)(wsum[0] + wsum[1] + wsum[2] + wsum[3]));
}

__global__ void k_final(const double* __restrict__ accum, float* __restrict__ out) {
    if (threadIdx.x == 0 && blockIdx.x == 0)
        out[0] = (float)(*accum / (double)(3.0 * (double)HH));
}

extern "C" void kernel_launch(void* const* d_in, const int* in_sizes, int n_in,
                              void* d_out, int out_size, void* d_ws, size_t ws_size,
                              hipStream_t stream) {
    const float* input  = (const float*)d_in[0];
    const float* target = (const float*)d_in[1];
    const float* ref    = (const float*)d_in[2];
    const float* msrc   = (const float*)d_in[3];
    const float* mtar   = (const float*)d_in[4];
    const int* i0 = (const int*)d_in[5];
    const int* i1 = (const int*)d_in[6];
    const int* i2 = (const int*)d_in[7];
    const int* i3 = (const int*)d_in[8];
    int nidx = in_sizes[5];

    char* ws = (char*)d_ws;
    double*   accum = (double*)(ws);
    uint32_t* hist8 = (uint32_t*)(ws + OFF_HIST8);
    uint32_t* gcnt  = (uint32_t*)(ws + OFF_GCNT);
    float*    table = (float*)(ws + OFF_TABLE);
    uint32_t* bits  = (uint32_t*)(ws + OFF_BITS);

    k_init<<<128, 256, 0, stream>>>((uint32_t*)ws);

    if (ws_size >= WS_FAST && (nidx % (SPT * 4)) == 0) {
        unsigned short* dlist = (unsigned short*)(ws + OFF_DLIST);
        unsigned short* rlist = (unsigned short*)(ws + OFF_RLIST);
        int noct = nidx / SPT;
        k_bucket<<<(noct + 255) / 256, 256, 0, stream>>>(
            i0, i1, i2, i3, dlist, rlist, gcnt, ref, msrc, target, mtar, hist8, bits,
            noct);
        k_bgather<<<2 * NBK, 256, 0, stream>>>(dlist, rlist, gcnt, ref, msrc, target,
                                               mtar, hist8, bits);
    } else {
        k_hist_fb<<<2048, 256, 0, stream>>>(target, ref, msrc, mtar, i0, i1, i2, i3,
                                            hist8, bits, nidx);
    }
    k_table<<<3, 256, 0, stream>>>(hist8, table);
    k_loss<<<2048, 256, 0, stream>>>(input, ref, msrc, bits, table, accum);
    k_final<<<1, 64, 0, stream>>>(accum, (float*)d_out);
}

// Round 7
// 149.252 us; speedup vs baseline: 1.1713x; 1.1713x over previous
//
#include <hip/hip_runtime.h>
#include <math.h>
#include <stdint.h>

#define H 2048
#define HH (H * H)
#define NB 256
#define NBK 512                 // buckets per side
#define RPIX (HH / NBK)         // 8192 pixels per region
#define RQUAD (RPIX / 4)        // 2048 quads per region
#define RLOG 13                 // log2(RPIX)
#define BCAP 4608               // mean 3906, sigma ~63 -> +11 sigma; spill path guards
#define BQUADS 2048             // quads per block in k_bucket (8192 samples/side)

// ws layout (fast path):
//   [0]       double accum               (8 B)
//   [64]      uint32 hist8[8][6*256]     (48 KiB)  8 slices to cut atomic chains
//   [49216]   uint32 gcnt[1024]          (4 KiB)   dst 0..511, ref 512..1023
//   [53312]   float  table[3][256]       (3 KiB)
//   [65536]   uint32 bits[HH/32]         (512 KiB) membership bitmask
//   [1 MiB]   u16    dlist[512][BCAP]    (4.5 MiB)
//   [6 MiB]   u16    rlist[512][BCAP]    (4.5 MiB)
#define OFF_HIST8 64
#define OFF_GCNT  49216
#define OFF_TABLE 53312
#define OFF_BITS  65536
#define OFF_DLIST ((size_t)1 << 20)
#define OFF_RLIST ((size_t)6 << 20)
#define WS_FAST   ((size_t)11 << 20)

__global__ void k_init(uint32_t* __restrict__ ws32) {
    int tid = blockIdx.x * blockDim.x + threadIdx.x;
    int stride = gridDim.x * blockDim.x;
    uint4 z = {0u, 0u, 0u, 0u};
    // zero [0, 56384): accum + hist8 + gcnt + table  (3524 uint4)
    uint4* a = (uint4*)ws32;
    for (int i = tid; i < 3524; i += stride) a[i] = z;
    // zero bits: 32768 uint4
    uint4* b = (uint4*)((char*)ws32 + OFF_BITS);
    for (int i = tid; i < 32768; i += stride) b[i] = z;
}

__device__ __forceinline__ float de_norm255(float x) {
    return fminf(fmaxf((x + 1.0f) * 0.5f, 0.0f), 1.0f) * 255.0f;
}

__device__ __forceinline__ uint32_t bin_of(float v, float m) {
    return (uint32_t)(de_norm255(v) * m);  // in [0,255], trunc==floor
}

#define E4(v, e) ((e) == 0 ? (v).x : (e) == 1 ? (v).y : (e) == 2 ? (v).z : (v).w)

// Two-pass partition, positions held in registers between passes.
// 512 threads x 4 quads = 8192 samples/side/block -> ~16 entries/bucket/block,
// written compactly (lbase + lcnt2++) => ~32B bursts, low write amplification.
__global__ __launch_bounds__(512) void k_bucket(
    const int* __restrict__ i0, const int* __restrict__ i1,
    const int* __restrict__ i2, const int* __restrict__ i3,
    unsigned short* __restrict__ dlist, unsigned short* __restrict__ rlist,
    uint32_t* __restrict__ gcnt,
    const float* __restrict__ ref, const float* __restrict__ msrc,
    const float* __restrict__ tgt, const float* __restrict__ mtar,
    uint32_t* __restrict__ hist8, uint32_t* __restrict__ bits, int nquad) {
    __shared__ uint32_t lcnt[2 * NBK];
    __shared__ uint32_t lbase[2 * NBK];
    __shared__ uint32_t lcnt2[2 * NBK];
    for (int i = threadIdx.x; i < 2 * NBK; i += blockDim.x) {
        lcnt[i] = 0u;
        lcnt2[i] = 0u;
    }
    __syncthreads();
    int pa[16], pb[16];
#pragma unroll
    for (int it = 0; it < 4; ++it) {
        int q = blockIdx.x * BQUADS + it * 512 + threadIdx.x;
        if (q < nquad) {
            int4 a = ((const int4*)i0)[q];
            int4 b = ((const int4*)i1)[q];
            int4 c = ((const int4*)i2)[q];
            int4 d = ((const int4*)i3)[q];
            pa[it * 4 + 0] = a.x * H + b.x; pa[it * 4 + 1] = a.y * H + b.y;
            pa[it * 4 + 2] = a.z * H + b.z; pa[it * 4 + 3] = a.w * H + b.w;
            pb[it * 4 + 0] = c.x * H + d.x; pb[it * 4 + 1] = c.y * H + d.y;
            pb[it * 4 + 2] = c.z * H + d.z; pb[it * 4 + 3] = c.w * H + d.w;
#pragma unroll
            for (int j = 0; j < 4; ++j) {
                atomicAdd(&lcnt[pa[it * 4 + j] >> RLOG], 1u);
                atomicAdd(&lcnt[NBK + (pb[it * 4 + j] >> RLOG)], 1u);
            }
        } else {
#pragma unroll
            for (int j = 0; j < 4; ++j) {
                pa[it * 4 + j] = -1;
                pb[it * 4 + j] = -1;
            }
        }
    }
    __syncthreads();
    for (int i = threadIdx.x; i < 2 * NBK; i += blockDim.x)
        lbase[i] = lcnt[i] ? atomicAdd(&gcnt[i], lcnt[i]) : 0u;
    __syncthreads();
    uint32_t* hs = hist8 + (blockIdx.x & 7) * 1536;
#pragma unroll
    for (int k = 0; k < 16; ++k) {
        int p = pa[k];
        if (p >= 0) {
            int bk = p >> RLOG;
            uint32_t s = lbase[bk] + atomicAdd(&lcnt2[bk], 1u);
            if (s < BCAP) {
                dlist[(size_t)bk * BCAP + s] = (unsigned short)(p & (RPIX - 1));
            } else {  // spill: statistically never
                float m = msrc[p];
                atomicOr(&bits[p >> 5], 1u << (p & 31));
#pragma unroll
                for (int c = 0; c < 3; ++c)
                    atomicAdd(&hs[c * NB + bin_of(ref[c * HH + p], m)], 1u);
            }
        }
        p = pb[k];
        if (p >= 0) {
            int bk = p >> RLOG;
            uint32_t s = lbase[NBK + bk] + atomicAdd(&lcnt2[NBK + bk], 1u);
            if (s < BCAP) {
                rlist[(size_t)bk * BCAP + s] = (unsigned short)(p & (RPIX - 1));
            } else {
                float m = mtar[p];
#pragma unroll
                for (int c = 0; c < 3; ++c)
                    atomicAdd(&hs[768 + c * NB + bin_of(tgt[c * HH + p], m)], 1u);
            }
        }
    }
}

// One block per (side, bucket). Phase A: scatter list into packed-u16 LDS counts.
// Phase B: stream region floats coalesced, add count-weighted histogram entries.
__global__ __launch_bounds__(256, 8) void k_bgather(
    const unsigned short* __restrict__ dlist, const unsigned short* __restrict__ rlist,
    const uint32_t* __restrict__ gcnt,
    const float* __restrict__ ref, const float* __restrict__ msrc,
    const float* __restrict__ tgt, const float* __restrict__ mtar,
    uint32_t* __restrict__ hist8, uint32_t* __restrict__ bits) {
    __shared__ uint32_t s_cnt[RPIX / 2];     // 16 KiB packed 2xu16 counts
    __shared__ uint32_t s_bits[RPIX / 32];   // 1 KiB membership
    __shared__ uint32_t s_h[3 * NB];         // 3 KiB histogram
    int bid = blockIdx.x;
    int isref = bid >= NBK;
    int b = isref ? bid - NBK : bid;
    const float* v = isref ? tgt : ref;
    const float* m = isref ? mtar : msrc;
    for (int i = threadIdx.x; i < RPIX / 2; i += blockDim.x) s_cnt[i] = 0u;
    for (int i = threadIdx.x; i < 3 * NB; i += blockDim.x) s_h[i] = 0u;
    if (!isref)
        for (int i = threadIdx.x; i < RPIX / 32; i += blockDim.x) s_bits[i] = 0u;
    __syncthreads();
    // Phase A: list -> LDS counts
    uint32_t n = min(gcnt[bid], (uint32_t)BCAP);
    const unsigned short* list = (isref ? rlist : dlist) + (size_t)b * BCAP;
    for (uint32_t i = threadIdx.x; i < n; i += blockDim.x) {
        uint32_t l = list[i];
        atomicAdd(&s_cnt[l >> 1], 1u << ((l & 1) * 16));
    }
    __syncthreads();
    // Phase B: stream region, weighted hist adds
    uint32_t z0 = 0, z1 = 0, z2 = 0;
    int qbase = b * RQUAD;
    for (int qi = threadIdx.x; qi < RQUAD; qi += blockDim.x) {
        uint2 cw = ((const uint2*)s_cnt)[qi];
        if ((cw.x | cw.y) == 0u) continue;
        float4 m4 = ((const float4*)m)[qbase + qi];
        float4 v0 = ((const float4*)(v))[qbase + qi];
        float4 v1 = ((const float4*)(v + HH))[qbase + qi];
        float4 v2 = ((const float4*)(v + 2 * HH))[qbase + qi];
        uint32_t cnts[4] = {cw.x & 0xffffu, cw.x >> 16, cw.y & 0xffffu, cw.y >> 16};
#pragma unroll
        for (int e = 0; e < 4; ++e) {
            uint32_t cn = cnts[e];
            if (!cn) continue;
            float mm = E4(m4, e);
            uint32_t b0 = bin_of(E4(v0, e), mm);
            uint32_t b1 = bin_of(E4(v1, e), mm);
            uint32_t b2 = bin_of(E4(v2, e), mm);
            if (b0) atomicAdd(&s_h[b0], cn); else z0 += cn;
            if (b1) atomicAdd(&s_h[NB + b1], cn); else z1 += cn;
            if (b2) atomicAdd(&s_h[2 * NB + b2], cn); else z2 += cn;
        }
        if (!isref) {
            uint32_t nib = (cnts[0] ? 1u : 0u) | (cnts[1] ? 2u : 0u) |
                           (cnts[2] ? 4u : 0u) | (cnts[3] ? 8u : 0u);
            atomicOr(&s_bits[qi >> 3], nib << ((qi & 7) * 4));
        }
    }
    if (z0) atomicAdd(&s_h[0], z0);
    if (z1) atomicAdd(&s_h[NB], z1);
    if (z2) atomicAdd(&s_h[2 * NB], z2);
    __syncthreads();
    uint32_t* hs = hist8 + (blockIdx.x & 7) * 1536 + (isref ? 768 : 0);
    for (int i = threadIdx.x; i < 3 * NB; i += blockDim.x)
        if (s_h[i]) atomicAdd(&hs[i], s_h[i]);
    if (!isref) {
        uint32_t* gb = bits + b * (RPIX / 32);
        for (int i = threadIdx.x; i < RPIX / 32; i += blockDim.x)
            if (s_bits[i]) atomicOr(&gb[i], s_bits[i]);
    }
}

// Monolithic fallback (any ws): gather floats via LLC + bits mask.
__global__ void k_hist_fb(const float* __restrict__ tgt, const float* __restrict__ ref,
                          const float* __restrict__ msrc, const float* __restrict__ mtar,
                          const int* __restrict__ i0, const int* __restrict__ i1,
                          const int* __restrict__ i2, const int* __restrict__ i3,
                          uint32_t* __restrict__ hist8, uint32_t* __restrict__ bits,
                          int nidx) {
    __shared__ uint32_t lh[6 * NB];
    for (int i = threadIdx.x; i < 6 * NB; i += blockDim.x) lh[i] = 0u;
    __syncthreads();
    int stride = gridDim.x * blockDim.x;
    for (int k = blockIdx.x * blockDim.x + threadIdx.x; k < nidx; k += stride) {
        int pa = i0[k] * H + i1[k];
        int pb = i2[k] * H + i3[k];
        float ms = msrc[pa];
        float mt = mtar[pb];
        atomicOr(&bits[pa >> 5], 1u << (pa & 31));
#pragma unroll
        for (int c = 0; c < 3; ++c) {
            atomicAdd(&lh[c * NB + bin_of(ref[c * HH + pa], ms)], 1u);
            atomicAdd(&lh[(3 + c) * NB + bin_of(tgt[c * HH + pb], mt)], 1u);
        }
    }
    __syncthreads();
    uint32_t* hs = hist8 + (blockIdx.x & 7) * 1536;
    for (int i = threadIdx.x; i < 6 * NB; i += blockDim.x)
        if (lh[i]) atomicAdd(&hs[i], lh[i]);
}

// 3 blocks (one per channel) x 256 threads; sums the 8 hist slices.
__global__ void k_table(const uint32_t* __restrict__ hist8, float* __restrict__ table) {
    int c = blockIdx.x;
    int t = threadIdx.x;
    __shared__ uint32_t cdd[NB], crr[NB];
    __shared__ float r[NB], a[NB];
    uint32_t sd = 0, sr = 0;
#pragma unroll
    for (int x = 0; x < 8; ++x) {
        sd += hist8[x * 1536 + c * NB + t];
        sr += hist8[x * 1536 + 768 + c * NB + t];
    }
    cdd[t] = sd;
    crr[t] = sr;
    __syncthreads();
    if (t == 0) {
        uint32_t s = 0;
        for (int i = 0; i < NB; ++i) { s += cdd[i]; cdd[i] = s; }
        s = 0;
        for (int i = 0; i < NB; ++i) { s += crr[i]; crr[i] = s; }
    }
    __syncthreads();
    float totd = (float)cdd[NB - 1];
    float totr = (float)crr[NB - 1];
    r[t] = (float)cdd[t] / totd;
    a[t] = (float)crr[t] / totr;
    __syncthreads();
    float out;
    if (t == 0) {
        out = 0.0f;
    } else if (t == NB - 1) {
        out = (float)(NB - 1);
    } else {
        float ri = r[t];
        int j = -1;
        for (int jj = 0; jj < NB - 1; ++jj) {
            if (ri >= a[jj] && ri <= a[jj + 1]) { j = jj; break; }
        }
        out = (j >= 0) ? (float)(j + 1) : (float)t;
    }
    table[c * NB + t] = out;
}

// float4-vectorized loss; membership from bits; table in LDS.
__global__ void k_loss(const float* __restrict__ inp, const float* __restrict__ ref,
                       const float* __restrict__ msrc, const uint32_t* __restrict__ bits,
                       const float* __restrict__ table, double* __restrict__ accum) {
    __shared__ float tl[3 * NB];
    for (int i = threadIdx.x; i < 3 * NB; i += blockDim.x) tl[i] = table[i];
    __syncthreads();
    float part = 0.0f;
    int stride = gridDim.x * blockDim.x;
    for (int q = blockIdx.x * blockDim.x + threadIdx.x; q < HH / 4; q += stride) {
        float4 m4 = ((const float4*)msrc)[q];
        uint32_t nib = bits[q >> 3] >> ((q & 7) * 4);
#pragma unroll
        for (int c = 0; c < 3; ++c) {
            float4 iv = ((const float4*)(inp + c * HH))[q];
            float4 rv = ((const float4*)(ref + c * HH))[q];
#pragma unroll
            for (int e = 0; e < 4; ++e) {
                float m = E4(m4, e);
                float im = de_norm255(E4(iv, e)) * m;
                float r = de_norm255(E4(rv, e)) * m;
                float match;
                if ((nib >> e) & 1u)
                    match = tl[c * NB + (int)fminf(fmaxf(r, 0.0f), 255.0f)];
                else
                    match = r;
                part += fabsf(im - match);
            }
        }
    }
#pragma unroll
    for (int off = 32; off > 0; off >>= 1) part += __shfl_down(part, off);
    __shared__ float wsum[4];
    int lane = threadIdx.x & 63;
    int wid = threadIdx.x >> 6;
    if (lane == 0) wsum[wid] = part;
    __syncthreads();
    if (threadIdx.x == 0)
        atomicAdd(accum, (double)(wsum[0] + wsum[1] + wsum[2] + wsum[3]));
}

__global__ void k_final(const double* __restrict__ accum, float* __restrict__ out) {
    if (threadIdx.x == 0 && blockIdx.x == 0)
        out[0] = (float)(*accum / (double)(3.0 * (double)HH));
}

extern "C" void kernel_launch(void* const* d_in, const int* in_sizes, int n_in,
                              void* d_out, int out_size, void* d_ws, size_t ws_size,
                              hipStream_t stream) {
    const float* input  = (const float*)d_in[0];
    const float* target = (const float*)d_in[1];
    const float* ref    = (const float*)d_in[2];
    const float* msrc   = (const float*)d_in[3];
    const float* mtar   = (const float*)d_in[4];
    const int* i0 = (const int*)d_in[5];
    const int* i1 = (const int*)d_in[6];
    const int* i2 = (const int*)d_in[7];
    const int* i3 = (const int*)d_in[8];
    int nidx = in_sizes[5];

    char* ws = (char*)d_ws;
    double*   accum = (double*)(ws);
    uint32_t* hist8 = (uint32_t*)(ws + OFF_HIST8);
    uint32_t* gcnt  = (uint32_t*)(ws + OFF_GCNT);
    float*    table = (float*)(ws + OFF_TABLE);
    uint32_t* bits  = (uint32_t*)(ws + OFF_BITS);

    k_init<<<256, 256, 0, stream>>>((uint32_t*)ws);

    if (ws_size >= WS_FAST && (nidx & 3) == 0) {
        unsigned short* dlist = (unsigned short*)(ws + OFF_DLIST);
        unsigned short* rlist = (unsigned short*)(ws + OFF_RLIST);
        int nquad = nidx / 4;
        k_bucket<<<(nquad + BQUADS - 1) / BQUADS, 512, 0, stream>>>(
            i0, i1, i2, i3, dlist, rlist, gcnt, ref, msrc, target, mtar, hist8, bits,
            nquad);
        k_bgather<<<2 * NBK, 256, 0, stream>>>(dlist, rlist, gcnt, ref, msrc, target,
                                               mtar, hist8, bits);
    } else {
        k_hist_fb<<<2048, 256, 0, stream>>>(target, ref, msrc, mtar, i0, i1, i2, i3,
                                            hist8, bits, nidx);
    }
    k_table<<<3, 256, 0, stream>>>(hist8, table);
    k_loss<<<2048, 256, 0, stream>>>(input, ref, msrc, bits, table, accum);
    k_final<<<1, 64, 0, stream>>>(accum, (float*)d_out);
}